// Round 1
// 355.057 us; speedup vs baseline: 1.0440x; 1.0440x over previous
//
#include <hip/hip_runtime.h>

// NeuralMapCell — ROUND 16. Theory: serialization, not BW, dominates (roofline
// floor ~35us vs 370us measured). conv1 v4: atomics -> 8 partial buffers +
// k_c1red (k_zero_c1 deleted); k-slice staged in LDS (inner loop all-LDS,
// uniform b128 broadcasts). Tail fused: r1red1+r1red2+small -> k_fused (1024
// thr, identical sum order); ctred folded into k_final. 12 launches -> 10.
//
// d_out = float[1049088]: c_t[256] r_t[256] new_mem[1048576].
// Scratch scr = out + 512 (1048576 floats capacity).
// Lifetime plan (stream-ordered):
//   conv1 writes c1p[8][32][4096] = scr[0 .. 1048576)          (all of scr)
//   c1red sums 8 chunks in-place -> c1 = scr[0 .. 131072)
//   conv2 reads c1, writes C2; everything later sits above or in dead c1.
#define SOFF_R1   0        // 128   (unused now, kept for reference)
#define SOFF_CT   128      // 256   (unused now)
#define SOFF_RT   384      // 256
#define SOFF_QT   640      // 256
#define SOFF_ST   896      // 256
#define SOFF_SC   1152     // 4096
#define SOFF_AT   5248     // 4096
#define SOFF_C2   140416   // 246016 conv2 out (64ch x 62x62)
#define SOFF_P1   386432   // 119168 r1 partials (931 x 128)
#define SOFF_PC   505600   // 4096   ct partials (16 x 256)
// end = 509696 <= 1048576 ✓   c1p chunks at c*131072, c=0..7.

#define FLAT  238144      // 64*61*61
#define NB_R1 931

__device__ __forceinline__ int read_idx(const int* p) {
    unsigned int u = (unsigned int)*p;
    int ex = (int)((u >> 23) & 0xFF);
    int v;
    if (ex >= 118 && ex <= 140) {
        union { unsigned int i; float f; } c; c.i = u;
        v = (int)(c.f + 0.5f);
    } else {
        v = (int)u;
    }
    return v < 0 ? 0 : (v > 63 ? 63 : v);
}

// ---- conv1 v4 (cross-corr, SAME, 3x3, 256->32): partials c1p[chunk][o][4096]
// grid (64, 8): bx = spatial 8x8 tile, by = 32-ch i-chunk. threads 256.
// LDS: halo 10x10x32 (pad 104) 13.3KB + k-slice [9][32i][32o] 36.9KB = 49KB.
__global__ __launch_bounds__(256) void k_conv1(const float* __restrict__ mem,
                                               const float* __restrict__ k1,
                                               float* __restrict__ c1p) {
    __shared__ float sm[32 * 104];          // [i][pix], pix padded 100->104
    __shared__ float sk[9 * 32 * 32];       // [tap][i][o]
    int t = threadIdx.x;
    int th = (blockIdx.x >> 3) * 8;         // tile origin h
    int tw = (blockIdx.x & 7) * 8;          // tile origin w
    int chunk = blockIdx.y;                 // 0..7, channels chunk*32..+32
    // stage 10x10 halo x 32 ch: 100 pixels x 8 float4-groups = 800 units
    for (int u = t; u < 800; u += 256) {
        int pix = u >> 3;
        int c4 = u & 7;
        int hh = th - 1 + pix / 10;
        int ww = tw - 1 + pix % 10;
        float4 v = make_float4(0.f, 0.f, 0.f, 0.f);
        if ((unsigned)hh < 64u && (unsigned)ww < 64u)
            v = *(const float4*)(mem + (size_t)(hh * 64 + ww) * 256
                                     + chunk * 32 + c4 * 4);
        int ib = c4 * 4;
        sm[(ib    ) * 104 + pix] = v.x;
        sm[(ib + 1) * 104 + pix] = v.y;
        sm[(ib + 2) * 104 + pix] = v.z;
        sm[(ib + 3) * 104 + pix] = v.w;
    }
    // stage k slice: 9 taps x contiguous 1024 floats (32i x 32o), 2304 float4
    for (int u = t; u < 2304; u += 256) {
        int tap = u >> 8;                   // 0..8
        int r   = u & 255;                  // float4 index within tap
        const float4* src = (const float4*)(k1 + (size_t)tap * 8192
                                               + (size_t)chunk * 1024);
        *(float4*)&sk[tap * 1024 + r * 4] = src[r];
    }
    __syncthreads();
    int lh = (t & 63) >> 3, lw = t & 7, og = t >> 6;
    float acc[8];
    #pragma unroll
    for (int j = 0; j < 8; ++j) acc[j] = 0.f;
    for (int dh = 0; dh < 3; ++dh)
        for (int dw = 0; dw < 3; ++dw) {
            int pixb = (lh + dh) * 10 + (lw + dw);
            const float* kt = sk + (dh * 3 + dw) * 1024 + og * 8;
            #pragma unroll 4
            for (int i = 0; i < 32; ++i) {
                float m = sm[i * 104 + pixb];
                float4 ka = *(const float4*)(kt + i * 32);
                float4 kb = *(const float4*)(kt + i * 32 + 4);
                acc[0] += m * ka.x; acc[1] += m * ka.y;
                acc[2] += m * ka.z; acc[3] += m * ka.w;
                acc[4] += m * kb.x; acc[5] += m * kb.y;
                acc[6] += m * kb.z; acc[7] += m * kb.w;
            }
        }
    int p = (th + lh) * 64 + tw + lw;
    float* dst = c1p + (size_t)chunk * 131072 + (size_t)(og * 8) * 4096 + p;
    #pragma unroll
    for (int j = 0; j < 8; ++j)
        dst[(size_t)j * 4096] = acc[j];
}

// ---- reduce 8 chunk-partials -> c1 (in-place into chunk 0; no aliasing:
// each thread reads/writes only its own idx).
__global__ __launch_bounds__(256) void k_c1red(float* __restrict__ c1p) {
    int idx = blockIdx.x * 256 + threadIdx.x;   // 512 x 256 = 131072
    float s = 0.f;
    #pragma unroll
    for (int c = 0; c < 8; ++c) s += c1p[(size_t)c * 131072 + idx];
    c1p[idx] = s;
}

// ---- conv2 (cross-corr, VALID, 3x3, 32->64): c2[o*3844 + h*62 + w]
__global__ __launch_bounds__(256) void k_conv2(const float* __restrict__ c1,
                                               const float* __restrict__ k2,
                                               float* __restrict__ c2) {
    int idx = blockIdx.x * 256 + threadIdx.x;
    if (idx >= 246016) return;
    int o = idx / 3844;
    int rem = idx % 3844;
    int h = rem / 62, w = rem % 62;
    float acc = 0.f;
    for (int dh = 0; dh < 3; ++dh)
        for (int dw = 0; dw < 3; ++dw) {
            const float* crow = c1 + (h + dh) * 64 + (w + dw);
            const float* krow = k2 + ((dh * 3 + dw) * 32) * 64 + o;
            for (int i = 0; i < 32; ++i)
                acc += crow[i * 4096] * krow[i * 64];
        }
    c2[o * 3844 + h * 62 + w] = acc;
}

// ---- pool + dense1 partials, NCHW flatten (unchanged)
__global__ __launch_bounds__(128) void k_r1p(const float* __restrict__ c2,
                                             const float* __restrict__ d1,
                                             float* __restrict__ p1) {
    __shared__ float pl[256];
    int j = threadIdx.x;
    int f0 = blockIdx.x * 256;
    int fmax = FLAT - f0; if (fmax > 256) fmax = 256;
    for (int s = j; s < fmax; s += 128) {
        int f = f0 + s;
        int o = f / 3721;
        int r = f % 3721;
        int h = r / 61, w = r % 61;
        const float* b = c2 + o * 3844 + h * 62 + w;
        pl[s] = 0.25f * (b[0] + b[1] + b[62] + b[63]);
    }
    __syncthreads();
    float acc = 0.f;
    for (int s = 0; s < fmax; ++s)
        acc += pl[s] * d1[(size_t)(f0 + s) * 128 + j];
    p1[blockIdx.x * 128 + j] = acc;
}

// ---- fused: r1 two-stage reduce + r_t / s_t / q_t. One block, 1024 threads.
// Summation orders identical to the previous 3-kernel version.
__global__ __launch_bounds__(1024) void k_fused(const float* __restrict__ p1,
                                                const float* __restrict__ d2,
                                                const float* __restrict__ inp,
                                                const float* __restrict__ ck,
                                                const float* __restrict__ rec,
                                                float* __restrict__ rt,
                                                float* __restrict__ qt,
                                                float* __restrict__ st) {
    __shared__ float p2s[8][128];
    __shared__ float s_r1[128], s_in[128], s_rt[256];
    int t = threadIdx.x;
    int j = t & 127, part = t >> 7;         // 8 parts x 117 blocks
    int b0 = part * 117;
    int b1 = b0 + 117; if (b1 > NB_R1) b1 = NB_R1;
    float s = 0.f;
    for (int b = b0; b < b1; ++b) s += p1[b * 128 + j];
    p2s[part][j] = s;
    if (t < 128) s_in[t] = inp[t];
    __syncthreads();
    if (t < 128) {
        float r = 0.f;
        #pragma unroll
        for (int c = 0; c < 8; ++c) r += p2s[c][t];
        s_r1[t] = r;
    }
    __syncthreads();
    if (t < 256) {
        float a = 0.f;
        for (int k = 0; k < 128; ++k) a += s_r1[k] * d2[k * 256 + t];
        rt[t] = a; s_rt[t] = a;
        float sv = 0.f;
        for (int k = 0; k < 128; ++k) sv += s_in[k] * rec[k * 256 + t];
        st[t] = sv;
    }
    __syncthreads();
    if (t < 256) {
        float q = 0.f;
        for (int k = 0; k < 128; ++k) q += s_in[k] * ck[k * 256 + t];
        for (int k = 0; k < 256; ++k) q += s_rt[k] * ck[(128 + k) * 256 + t];
        qt[t] = q;
    }
}

// ---- scores (unchanged)
__global__ __launch_bounds__(256) void k_scores(const float* __restrict__ qt,
                                                const float* __restrict__ mem,
                                                float* __restrict__ scores) {
    __shared__ float q[256];
    int t = threadIdx.x;
    q[t] = qt[t];
    __syncthreads();
    int wave = t >> 6, lane = t & 63;
    int base = (blockIdx.x * 4 + wave) * 16;
    float qx = q[lane * 4], qy = q[lane * 4 + 1],
          qz = q[lane * 4 + 2], qw = q[lane * 4 + 3];
    for (int r = 0; r < 16; ++r) {
        int p = base + r;
        float4 m = *(const float4*)(mem + (size_t)p * 256 + lane * 4);
        float acc = m.x * qx + m.y * qy + m.z * qz + m.w * qw;
        for (int off = 32; off; off >>= 1) acc += __shfl_down(acc, off);
        if (lane == 0) scores[p] = acc;
    }
}

__global__ __launch_bounds__(256) void k_softmax(const float* __restrict__ scores,
                                                 float* __restrict__ at) {
    __shared__ float red[256];
    int t = threadIdx.x;
    float m = -1e30f;
    for (int i = t; i < 4096; i += 256) m = fmaxf(m, scores[i]);
    red[t] = m; __syncthreads();
    for (int s = 128; s; s >>= 1) { if (t < s) red[t] = fmaxf(red[t], red[t + s]); __syncthreads(); }
    float mx = red[0]; __syncthreads();
    float sum = 0.f;
    for (int i = t; i < 4096; i += 256) sum += expf(scores[i] - mx);
    red[t] = sum; __syncthreads();
    for (int s = 128; s; s >>= 1) { if (t < s) red[t] += red[t + s]; __syncthreads(); }
    float inv = 1.f / red[0];
    for (int i = t; i < 4096; i += 256) at[i] = expf(scores[i] - mx) * inv;
}

__global__ __launch_bounds__(256) void k_ctp(const float* __restrict__ at,
                                             const float* __restrict__ mem,
                                             float* __restrict__ pc) {
    __shared__ float a[256];
    int t = threadIdx.x;
    int p0 = blockIdx.x * 256;
    a[t] = at[p0 + t];
    __syncthreads();
    float acc = 0.f;
    for (int pp = 0; pp < 256; ++pp)
        acc += a[pp] * mem[(size_t)(p0 + pp) * 256 + t];
    pc[blockIdx.x * 256 + t] = acc;
}

// ---- final, with ct reduction folded in (same order as old k_ctred)
__global__ __launch_bounds__(256) void k_final(const float* __restrict__ rt,
                                               const float* __restrict__ st,
                                               const float* __restrict__ pc,
                                               const float* __restrict__ mem,
                                               const float* __restrict__ rec,
                                               const int* __restrict__ px,
                                               const int* __restrict__ py,
                                               float* __restrict__ out) {
    __shared__ float s_diff[256], red[256];
    int t = threadIdx.x;
    int x = read_idx(px), y = read_idx(py);
    int pxy = x * 64 + y;
    float ctv = 0.f;
    #pragma unroll
    for (int b = 0; b < 16; ++b) ctv += pc[b * 256 + t];
    float stv = st[t], rtv = rt[t];
    float memt = mem[(size_t)pxy * 256 + t];
    red[t] = stv * rtv; __syncthreads();
    for (int s = 128; s; s >>= 1) { if (t < s) red[t] += red[t + s]; __syncthreads(); }
    float gimp = red[0]; __syncthreads();
    red[t] = stv * ctv; __syncthreads();
    for (int s = 128; s; s >>= 1) { if (t < s) red[t] += red[t + s]; __syncthreads(); }
    float limp = red[0];
    s_diff[t] = memt - stv;
    __syncthreads();
    float d = 0.f;
    for (int k = 0; k < 256; ++k)
        d += s_diff[k] * rec[(128 + k) * 256 + t];
    float frac = limp / (limp + gimp);
    float nv = memt + frac * d;
    out[t] = ctv;
    out[256 + t] = rtv;
    out[512 + (size_t)t * 4096 + pxy] = nv;
}

// ---- transpose (unchanged)
__global__ __launch_bounds__(256) void k_transpose(const float* __restrict__ mem,
                                                   const int* __restrict__ px,
                                                   const int* __restrict__ py,
                                                   float* __restrict__ outm) {
    __shared__ float tile[64][65];
    int t = threadIdx.x;
    int p0 = blockIdx.x * 64;
    int u0 = blockIdx.y * 64;
    int x = read_idx(px), y = read_idx(py);
    int pxy = x * 64 + y;
    int lane = t & 63, grp = t >> 6;
    for (int r = 0; r < 16; ++r) {
        int pr = grp + r * 4;
        tile[pr][lane] = mem[(size_t)(p0 + pr) * 256 + u0 + lane];
    }
    __syncthreads();
    for (int r = 0; r < 16; ++r) {
        int ur = grp + r * 4;
        if (p0 + lane != pxy)
            outm[(size_t)(u0 + ur) * 4096 + p0 + lane] = tile[lane][ur];
    }
}

extern "C" void kernel_launch(void* const* d_in, const int* in_sizes, int n_in,
                              void* d_out, int out_size, void* d_ws, size_t ws_size,
                              hipStream_t stream) {
    const float* inp = (const float*)d_in[0];
    const float* mem = (const float*)d_in[1];
    const float* k1  = (const float*)d_in[2];
    const float* k2  = (const float*)d_in[3];
    const float* d1  = (const float*)d_in[4];
    const float* d2  = (const float*)d_in[5];
    const float* ck  = (const float*)d_in[6];
    const float* rec = (const float*)d_in[7];
    const int* px = (const int*)d_in[8];
    const int* py = (const int*)d_in[9];
    float* out = (float*)d_out;
    float* scr = out + 512;
    (void)d_ws; (void)ws_size;

    k_conv1<<<dim3(64, 8), 256, 0, stream>>>(mem, k1, scr);       // c1p @ scr+0
    k_c1red<<<512, 256, 0, stream>>>(scr);                        // c1 @ scr+0
    k_conv2<<<961, 256, 0, stream>>>(scr, k2, scr + SOFF_C2);
    k_r1p<<<NB_R1, 128, 0, stream>>>(scr + SOFF_C2, d1, scr + SOFF_P1);
    k_fused<<<1, 1024, 0, stream>>>(scr + SOFF_P1, d2, inp, ck, rec,
                                    scr + SOFF_RT, scr + SOFF_QT, scr + SOFF_ST);
    k_scores<<<64, 256, 0, stream>>>(scr + SOFF_QT, mem, scr + SOFF_SC);
    k_softmax<<<1, 256, 0, stream>>>(scr + SOFF_SC, scr + SOFF_AT);
    k_ctp<<<16, 256, 0, stream>>>(scr + SOFF_AT, mem, scr + SOFF_PC);
    k_final<<<1, 256, 0, stream>>>(scr + SOFF_RT, scr + SOFF_ST, scr + SOFF_PC,
                                   mem, rec, px, py, out);
    k_transpose<<<dim3(64, 4), 256, 0, stream>>>(mem, px, py, out + 512);
}

// Round 2
// 350.455 us; speedup vs baseline: 1.0577x; 1.0131x over previous
//
#include <hip/hip_runtime.h>

// NeuralMapCell — ROUND 17. Theory: memory stages are under-occupied /
// under-vectorized. r1p v2: 256 thr, float4 d1 loads (4x in-flight bytes),
// LDS 8-group reduce. scores v2: 256 blocks. ctp v2: 64 blocks. conv2 v2:
// LDS-tiled (halo + k2 slice in LDS), c1red fused into staging, C2/P1 in
// d_ws (fallback to scr + separate c1red if ws too small). conv1 unchanged.
//
// d_out = float[1049088]: c_t[256] r_t[256] new_mem[1048576].
// scr = out + 512 (1048576 floats). c1p = scr[0..1048576) lives conv1->conv2.
// After conv2, c1p is dead; small buffers live in its low region:
#define SOFF_RT   384      // 256
#define SOFF_QT   640      // 256
#define SOFF_ST   896      // 256
#define SOFF_SC   1152     // 4096
#define SOFF_AT   5248     // 4096
#define SOFF_PC   9344     // 64 x 256 = 16384 -> ends 25728  ✓
// Path B (no usable ws): c1red compacts c1p to [0..131072), then
#define SOFF_C2B  140416   // 246016
#define SOFF_P1B  386432   // 119168  -> ends 505600 ✓

#define FLAT  238144      // 64*61*61
#define NB_R1 931

__device__ __forceinline__ int read_idx(const int* p) {
    unsigned int u = (unsigned int)*p;
    int ex = (int)((u >> 23) & 0xFF);
    int v;
    if (ex >= 118 && ex <= 140) {
        union { unsigned int i; float f; } c; c.i = u;
        v = (int)(c.f + 0.5f);
    } else {
        v = (int)u;
    }
    return v < 0 ? 0 : (v > 63 ? 63 : v);
}

// ---- conv1 v4 (unchanged from r16): partials c1p[chunk][o][4096]
__global__ __launch_bounds__(256) void k_conv1(const float* __restrict__ mem,
                                               const float* __restrict__ k1,
                                               float* __restrict__ c1p) {
    __shared__ float sm[32 * 104];
    __shared__ __align__(16) float sk[9 * 32 * 32];
    int t = threadIdx.x;
    int th = (blockIdx.x >> 3) * 8;
    int tw = (blockIdx.x & 7) * 8;
    int chunk = blockIdx.y;
    for (int u = t; u < 800; u += 256) {
        int pix = u >> 3;
        int c4 = u & 7;
        int hh = th - 1 + pix / 10;
        int ww = tw - 1 + pix % 10;
        float4 v = make_float4(0.f, 0.f, 0.f, 0.f);
        if ((unsigned)hh < 64u && (unsigned)ww < 64u)
            v = *(const float4*)(mem + (size_t)(hh * 64 + ww) * 256
                                     + chunk * 32 + c4 * 4);
        int ib = c4 * 4;
        sm[(ib    ) * 104 + pix] = v.x;
        sm[(ib + 1) * 104 + pix] = v.y;
        sm[(ib + 2) * 104 + pix] = v.z;
        sm[(ib + 3) * 104 + pix] = v.w;
    }
    for (int u = t; u < 2304; u += 256) {
        int tap = u >> 8;
        int r   = u & 255;
        const float4* src = (const float4*)(k1 + (size_t)tap * 8192
                                               + (size_t)chunk * 1024);
        *(float4*)&sk[tap * 1024 + r * 4] = src[r];
    }
    __syncthreads();
    int lh = (t & 63) >> 3, lw = t & 7, og = t >> 6;
    float acc[8];
    #pragma unroll
    for (int j = 0; j < 8; ++j) acc[j] = 0.f;
    for (int dh = 0; dh < 3; ++dh)
        for (int dw = 0; dw < 3; ++dw) {
            int pixb = (lh + dh) * 10 + (lw + dw);
            const float* kt = sk + (dh * 3 + dw) * 1024 + og * 8;
            #pragma unroll 4
            for (int i = 0; i < 32; ++i) {
                float m = sm[i * 104 + pixb];
                float4 ka = *(const float4*)(kt + i * 32);
                float4 kb = *(const float4*)(kt + i * 32 + 4);
                acc[0] += m * ka.x; acc[1] += m * ka.y;
                acc[2] += m * ka.z; acc[3] += m * ka.w;
                acc[4] += m * kb.x; acc[5] += m * kb.y;
                acc[6] += m * kb.z; acc[7] += m * kb.w;
            }
        }
    int p = (th + lh) * 64 + tw + lw;
    float* dst = c1p + (size_t)chunk * 131072 + (size_t)(og * 8) * 4096 + p;
    #pragma unroll
    for (int j = 0; j < 8; ++j)
        dst[(size_t)j * 4096] = acc[j];
}

// ---- Path-B only: reduce 8 chunk-partials in place (chunk order ascending).
__global__ __launch_bounds__(256) void k_c1red(float* __restrict__ c1p) {
    int idx = blockIdx.x * 256 + threadIdx.x;
    float s = 0.f;
    #pragma unroll
    for (int c = 0; c < 8; ++c) s += c1p[(size_t)c * 131072 + idx];
    c1p[idx] = s;
}

// ---- conv2 v2: LDS-tiled. grid (64 tiles, 4 o-groups of 16). 256 thr:
// pix = t&63 (8x8), og = t>>6 -> 4 outputs o = o0+og*4..+3.
// Staging sums nchunks c1p partials (ascending c == k_c1red order).
__global__ __launch_bounds__(256) void k_conv2(const float* __restrict__ c1p,
                                               const float* __restrict__ k2,
                                               float* __restrict__ c2,
                                               int nchunks) {
    __shared__ float sm[32 * 104];          // [i][pix 10x10 pad 104]
    __shared__ __align__(16) float sk2[9 * 32 * 16];  // [tap][i][o-slice 16]
    int t = threadIdx.x;
    int th = (blockIdx.x >> 3) * 8;
    int tw = (blockIdx.x & 7) * 8;
    int o0 = blockIdx.y * 16;
    for (int u = t; u < 3200; u += 256) {
        int i = u / 100;
        int pix = u % 100;
        int hh = th + pix / 10;
        int ww = tw + pix % 10;
        float v = 0.f;
        if (hh < 64 && ww < 64) {
            const float* p = c1p + (size_t)i * 4096 + hh * 64 + ww;
            for (int c = 0; c < nchunks; ++c)
                v += p[(size_t)c * 131072];
        }
        sm[i * 104 + pix] = v;
    }
    for (int u = t; u < 1152; u += 256) {   // 9*32*16/4 float4
        int tap = u >> 7;
        int r = u & 127;
        int i = r >> 2, o4 = r & 3;
        *(float4*)&sk2[tap * 512 + i * 16 + o4 * 4] =
            *(const float4*)(k2 + (size_t)tap * 2048 + i * 64 + o0 + o4 * 4);
    }
    __syncthreads();
    int pix = t & 63;
    int lh = pix >> 3, lw = pix & 7, og = t >> 6;
    float acc[4] = {0.f, 0.f, 0.f, 0.f};
    for (int dh = 0; dh < 3; ++dh)
        for (int dw = 0; dw < 3; ++dw) {
            int pixb = (lh + dh) * 10 + (lw + dw);
            const float* kt = sk2 + (dh * 3 + dw) * 512 + og * 4;
            #pragma unroll 8
            for (int i = 0; i < 32; ++i) {
                float m = sm[i * 104 + pixb];
                float4 kv = *(const float4*)(kt + i * 16);
                acc[0] += m * kv.x; acc[1] += m * kv.y;
                acc[2] += m * kv.z; acc[3] += m * kv.w;
            }
        }
    int h = th + lh, w = tw + lw;
    if (h < 62 && w < 62) {
        #pragma unroll
        for (int j = 0; j < 4; ++j)
            c2[(size_t)(o0 + og * 4 + j) * 3844 + h * 62 + w] = acc[j];
    }
}

// ---- pool + dense1 partials v2: float4 d1 loads, 8-way s-split + LDS reduce.
__global__ __launch_bounds__(256) void k_r1p(const float* __restrict__ c2,
                                             const float* __restrict__ d1,
                                             float* __restrict__ p1) {
    __shared__ float pl[256];
    __shared__ __align__(16) float sred[8][32][4];
    int t = threadIdx.x;
    int f0 = blockIdx.x * 256;
    int fmax = FLAT - f0; if (fmax > 256) fmax = 256;
    for (int s = t; s < fmax; s += 256) {
        int f = f0 + s;
        int o = f / 3721;
        int r = f % 3721;
        int h = r / 61, w = r % 61;
        const float* b = c2 + (size_t)o * 3844 + h * 62 + w;
        pl[s] = 0.25f * (b[0] + b[1] + b[62] + b[63]);
    }
    __syncthreads();
    int jq = t & 31, g = t >> 5;
    float4 a = make_float4(0.f, 0.f, 0.f, 0.f);
    for (int s = g; s < fmax; s += 8) {
        float m = pl[s];
        float4 dv = *(const float4*)(d1 + (size_t)(f0 + s) * 128 + jq * 4);
        a.x += m * dv.x; a.y += m * dv.y; a.z += m * dv.z; a.w += m * dv.w;
    }
    *(float4*)sred[g][jq] = a;
    __syncthreads();
    if (t < 32) {
        float4 s = make_float4(0.f, 0.f, 0.f, 0.f);
        #pragma unroll
        for (int gg = 0; gg < 8; ++gg) {
            float4 v = *(const float4*)sred[gg][t];
            s.x += v.x; s.y += v.y; s.z += v.z; s.w += v.w;
        }
        *(float4*)(p1 + (size_t)blockIdx.x * 128 + t * 4) = s;
    }
}

// ---- fused r1 reduce + r_t / s_t / q_t (unchanged from r16)
__global__ __launch_bounds__(1024) void k_fused(const float* __restrict__ p1,
                                                const float* __restrict__ d2,
                                                const float* __restrict__ inp,
                                                const float* __restrict__ ck,
                                                const float* __restrict__ rec,
                                                float* __restrict__ rt,
                                                float* __restrict__ qt,
                                                float* __restrict__ st) {
    __shared__ float p2s[8][128];
    __shared__ float s_r1[128], s_in[128], s_rt[256];
    int t = threadIdx.x;
    int j = t & 127, part = t >> 7;
    int b0 = part * 117;
    int b1 = b0 + 117; if (b1 > NB_R1) b1 = NB_R1;
    float s = 0.f;
    for (int b = b0; b < b1; ++b) s += p1[b * 128 + j];
    p2s[part][j] = s;
    if (t < 128) s_in[t] = inp[t];
    __syncthreads();
    if (t < 128) {
        float r = 0.f;
        #pragma unroll
        for (int c = 0; c < 8; ++c) r += p2s[c][t];
        s_r1[t] = r;
    }
    __syncthreads();
    if (t < 256) {
        float a = 0.f;
        for (int k = 0; k < 128; ++k) a += s_r1[k] * d2[k * 256 + t];
        rt[t] = a; s_rt[t] = a;
        float sv = 0.f;
        for (int k = 0; k < 128; ++k) sv += s_in[k] * rec[k * 256 + t];
        st[t] = sv;
    }
    __syncthreads();
    if (t < 256) {
        float q = 0.f;
        for (int k = 0; k < 128; ++k) q += s_in[k] * ck[k * 256 + t];
        for (int k = 0; k < 256; ++k) q += s_rt[k] * ck[(128 + k) * 256 + t];
        qt[t] = q;
    }
}

// ---- scores v2: 256 blocks, 4 rows/wave (same per-row numerics)
__global__ __launch_bounds__(256) void k_scores(const float* __restrict__ qt,
                                                const float* __restrict__ mem,
                                                float* __restrict__ scores) {
    __shared__ float q[256];
    int t = threadIdx.x;
    q[t] = qt[t];
    __syncthreads();
    int wave = t >> 6, lane = t & 63;
    int base = blockIdx.x * 16 + wave * 4;
    float qx = q[lane * 4], qy = q[lane * 4 + 1],
          qz = q[lane * 4 + 2], qw = q[lane * 4 + 3];
    for (int r = 0; r < 4; ++r) {
        int p = base + r;
        float4 m = *(const float4*)(mem + (size_t)p * 256 + lane * 4);
        float acc = m.x * qx + m.y * qy + m.z * qz + m.w * qw;
        for (int off = 32; off; off >>= 1) acc += __shfl_down(acc, off);
        if (lane == 0) scores[p] = acc;
    }
}

__global__ __launch_bounds__(256) void k_softmax(const float* __restrict__ scores,
                                                 float* __restrict__ at) {
    __shared__ float red[256];
    int t = threadIdx.x;
    float m = -1e30f;
    for (int i = t; i < 4096; i += 256) m = fmaxf(m, scores[i]);
    red[t] = m; __syncthreads();
    for (int s = 128; s; s >>= 1) { if (t < s) red[t] = fmaxf(red[t], red[t + s]); __syncthreads(); }
    float mx = red[0]; __syncthreads();
    float sum = 0.f;
    for (int i = t; i < 4096; i += 256) sum += expf(scores[i] - mx);
    red[t] = sum; __syncthreads();
    for (int s = 128; s; s >>= 1) { if (t < s) red[t] += red[t + s]; __syncthreads(); }
    float inv = 1.f / red[0];
    for (int i = t; i < 4096; i += 256) at[i] = expf(scores[i] - mx) * inv;
}

// ---- ctp v2: 64 blocks x 64 p each (overall p-order ascending, unchanged)
__global__ __launch_bounds__(256) void k_ctp(const float* __restrict__ at,
                                             const float* __restrict__ mem,
                                             float* __restrict__ pc) {
    __shared__ float a[64];
    int t = threadIdx.x;
    int p0 = blockIdx.x * 64;
    if (t < 64) a[t] = at[p0 + t];
    __syncthreads();
    float acc = 0.f;
    #pragma unroll 8
    for (int pp = 0; pp < 64; ++pp)
        acc += a[pp] * mem[(size_t)(p0 + pp) * 256 + t];
    pc[blockIdx.x * 256 + t] = acc;
}

// ---- final (ct reduce now 64 partials)
__global__ __launch_bounds__(256) void k_final(const float* __restrict__ rt,
                                               const float* __restrict__ st,
                                               const float* __restrict__ pc,
                                               const float* __restrict__ mem,
                                               const float* __restrict__ rec,
                                               const int* __restrict__ px,
                                               const int* __restrict__ py,
                                               float* __restrict__ out) {
    __shared__ float s_diff[256], red[256];
    int t = threadIdx.x;
    int x = read_idx(px), y = read_idx(py);
    int pxy = x * 64 + y;
    float ctv = 0.f;
    #pragma unroll 8
    for (int b = 0; b < 64; ++b) ctv += pc[b * 256 + t];
    float stv = st[t], rtv = rt[t];
    float memt = mem[(size_t)pxy * 256 + t];
    red[t] = stv * rtv; __syncthreads();
    for (int s = 128; s; s >>= 1) { if (t < s) red[t] += red[t + s]; __syncthreads(); }
    float gimp = red[0]; __syncthreads();
    red[t] = stv * ctv; __syncthreads();
    for (int s = 128; s; s >>= 1) { if (t < s) red[t] += red[t + s]; __syncthreads(); }
    float limp = red[0];
    s_diff[t] = memt - stv;
    __syncthreads();
    float d = 0.f;
    for (int k = 0; k < 256; ++k)
        d += s_diff[k] * rec[(128 + k) * 256 + t];
    float frac = limp / (limp + gimp);
    float nv = memt + frac * d;
    out[t] = ctv;
    out[256 + t] = rtv;
    out[512 + (size_t)t * 4096 + pxy] = nv;
}

// ---- transpose (unchanged)
__global__ __launch_bounds__(256) void k_transpose(const float* __restrict__ mem,
                                                   const int* __restrict__ px,
                                                   const int* __restrict__ py,
                                                   float* __restrict__ outm) {
    __shared__ float tile[64][65];
    int t = threadIdx.x;
    int p0 = blockIdx.x * 64;
    int u0 = blockIdx.y * 64;
    int x = read_idx(px), y = read_idx(py);
    int pxy = x * 64 + y;
    int lane = t & 63, grp = t >> 6;
    for (int r = 0; r < 16; ++r) {
        int pr = grp + r * 4;
        tile[pr][lane] = mem[(size_t)(p0 + pr) * 256 + u0 + lane];
    }
    __syncthreads();
    for (int r = 0; r < 16; ++r) {
        int ur = grp + r * 4;
        if (p0 + lane != pxy)
            outm[(size_t)(u0 + ur) * 4096 + p0 + lane] = tile[lane][ur];
    }
}

extern "C" void kernel_launch(void* const* d_in, const int* in_sizes, int n_in,
                              void* d_out, int out_size, void* d_ws, size_t ws_size,
                              hipStream_t stream) {
    const float* inp = (const float*)d_in[0];
    const float* mem = (const float*)d_in[1];
    const float* k1  = (const float*)d_in[2];
    const float* k2  = (const float*)d_in[3];
    const float* d1  = (const float*)d_in[4];
    const float* d2  = (const float*)d_in[5];
    const float* ck  = (const float*)d_in[6];
    const float* rec = (const float*)d_in[7];
    const int* px = (const int*)d_in[8];
    const int* py = (const int*)d_in[9];
    float* out = (float*)d_out;
    float* scr = out + 512;

    bool useWs = (d_ws != nullptr) &&
                 (ws_size >= (size_t)(246016 + 119168) * sizeof(float));
    float* C2 = useWs ? (float*)d_ws           : scr + SOFF_C2B;
    float* P1 = useWs ? (float*)d_ws + 246016  : scr + SOFF_P1B;

    k_conv1<<<dim3(64, 8), 256, 0, stream>>>(mem, k1, scr);   // c1p @ scr
    int nch = 8;
    if (!useWs) { k_c1red<<<512, 256, 0, stream>>>(scr); nch = 1; }
    k_conv2<<<dim3(64, 4), 256, 0, stream>>>(scr, k2, C2, nch);
    k_r1p<<<NB_R1, 256, 0, stream>>>(C2, d1, P1);
    k_fused<<<1, 1024, 0, stream>>>(P1, d2, inp, ck, rec,
                                    scr + SOFF_RT, scr + SOFF_QT, scr + SOFF_ST);
    k_scores<<<256, 256, 0, stream>>>(scr + SOFF_QT, mem, scr + SOFF_SC);
    k_softmax<<<1, 256, 0, stream>>>(scr + SOFF_SC, scr + SOFF_AT);
    k_ctp<<<64, 256, 0, stream>>>(scr + SOFF_AT, mem, scr + SOFF_PC);
    k_final<<<1, 256, 0, stream>>>(scr + SOFF_RT, scr + SOFF_ST, scr + SOFF_PC,
                                   mem, rec, px, py, out);
    k_transpose<<<dim3(64, 4), 256, 0, stream>>>(mem, px, py, out + 512);
}